// Round 6
// baseline (2457.542 us; speedup 1.0000x reference)
//
#include <hip/hip_runtime.h>
#include <hip/hip_bf16.h>

#define BATCH 64
#define SEQT  2048
#define FEAT  64
#define HID   128
#define G4    512              // 4*HID
#define CHUNK 16
#define NCHUNK (SEQT / CHUNK)  // 128
#define XSP  68                // xs row stride (floats), padded vs 64
#define H1P  136               // h1x row stride (shorts), padded vs 128
#define XZP  516               // xzbuf row stride (floats), padded vs 512

using short8  = __attribute__((ext_vector_type(8))) short;   // 8 x bf16 (4 VGPRs)
using floatx4 = __attribute__((ext_vector_type(4))) float;   // MFMA C/D

// lgkm-only barrier: no vmcnt(0) drain (prefetch loads / output stores stay in
// flight). Single asm block with memory clobber => compiler can't move LDS ops
// across it; all uses are in uniform control flow.
#define BAR_LGKM() asm volatile("s_waitcnt lgkmcnt(0)\n\ts_barrier" ::: "memory")

// ---------- math helpers ----------
__device__ __forceinline__ float sigmoidf_(float x) {
    return __builtin_amdgcn_rcpf(1.0f + __expf(-x));
}
__device__ __forceinline__ float seluf_(float x) {
    const float a = 1.6732632423543772f;
    const float s = 1.0507009873554805f;
    return x > 0.0f ? s * x : s * a * (__expf(x) - 1.0f);
}
// fp32 -> bf16 bits, round-to-nearest-even
__device__ __forceinline__ unsigned short f2bf_(float f) {
    unsigned u = __float_as_uint(f);
    u += 0x7FFFu + ((u >> 16) & 1u);
    return (unsigned short)(u >> 16);
}

// ---------- weight pre-conversion: W1/W2 -> fragment-layout bf16 in ws ----------
// Fragment index fi = ((j*4+quad)*KC + kc)*4 + g ; each frag = 8 bf16 covering
// rows k = kc*32 + quad*8 + [0,8), col = g*128 + j of W[k][g*128+j].
// W1: KC=2 -> 4096 frags at ws[0..]; W2: KC=4 -> 8192 frags at ws[32768 shorts..].
__global__ __launch_bounds__(256) void prep_weights(const float* __restrict__ W1,
                                                    const float* __restrict__ W2,
                                                    unsigned short* __restrict__ wsf) {
    int idx = blockIdx.x * 256 + threadIdx.x;      // 48*256 = 12288 frags total
    int KC, fi, obase;
    const float* src;
    if (idx < 4096) { KC = 2; src = W1; fi = idx;        obase = 0; }
    else            { KC = 4; src = W2; fi = idx - 4096; obase = 4096 * 8; }
    int g  = fi & 3;
    int r  = fi >> 2;
    int kc = r % KC;
    int p  = r / KC;
    int q  = p & 3;
    int j  = p >> 2;
    short8 v;
#pragma unroll
    for (int jj = 0; jj < 8; ++jj)
        v[jj] = (short)f2bf_(src[(size_t)(kc * 32 + q * 8 + jj) * G4 + g * 128 + j]);
    *(short8*)&wsf[obase + fi * 8] = v;
}

// ---------- fused two-layer LSTM, both layers in ONE block ----------
// 64 blocks x 1024 threads (16 waves = 4 waves/SIMD; needs <=128 regs/wave).
// Waves 0-7: layer 1 on chunk c. Waves 8-15: layer 2 on chunk c-1.
// The shared per-step barrier enforces the 1-chunk pipeline skew; h1 flows
// through an LDS double-buffer h1x[2] -- no global handoff, no flags, no
// atomics, no cross-CU latency. Each SIMD hosts 2 l1-waves + 2 l2-waves whose
// stall phases interleave (R1 showed 1 wave/SIMD exposes the full latency
// chain; R0's 2 lockstep waves only partially covered it).
// Register budget: U-frags 64 + af 16 + acc 16 + misc ~25 < 128. W-frags are
// re-loaded from ws (L2-resident, fragment-layout bf16) once per chunk,
// kc-batched so only 16 regs are live.
__global__ __launch_bounds__(1024)
void fused_lstm(const float* __restrict__ x,                 // [B][T][64] fp32
                const float* __restrict__ U1,                // [128][512] fp32
                const float* __restrict__ b1,                // [512]
                const float* __restrict__ U2,
                const float* __restrict__ b2,
                const unsigned short* __restrict__ wsf,      // frag-layout W1|W2 bf16
                float* __restrict__ out) {                   // [B][T][128] fp32
    const int  b   = (int)blockIdx.x;
    const int tid  = threadIdx.x;
    const int w    = tid >> 6;          // wave 0..15
    const bool l2w = w >= 8;
    const int  wl  = w & 7;             // wave within layer
    const int lane = tid & 63;
    const int c16  = lane & 15;
    const int quad = lane >> 4;
    const int j    = wl * 16 + c16;     // owned hidden column (0..127)

    __shared__ __align__(16) short hA1[2][HID];          // l1 h ping-pong (bf16)
    __shared__ __align__(16) short hA2[2][HID];          // l2 h ping-pong
    __shared__ __align__(16) float xz1[CHUNK * XZP];     // l1 z-pre fp32, padded
    __shared__ __align__(16) float xz2[CHUNK * XZP];     // l2 z-pre fp32
    __shared__ __align__(16) float xs[CHUNK * XSP];      // x chunk staged (padded)
    __shared__ __align__(16) short h1x[2][CHUNK * H1P];  // h1 chunk double-buffer

    // ---- stage recurrent-weight fragments U (l1->U1, l2->U2), K=128 ----
    const float* U = l2w ? U2 : U1;
    short8 bfrag[4][4];                 // [kc][gate]
#pragma unroll
    for (int g = 0; g < 4; ++g) {
        const float* Ucol = U + (size_t)(g * 128 + j);
#pragma unroll
        for (int kc = 0; kc < 4; ++kc) {
            short8 v;
#pragma unroll
            for (int jj = 0; jj < 8; ++jj) {
                int k = kc * 32 + quad * 8 + jj;
                v[jj] = (short)f2bf_(Ucol[(size_t)k * G4]);
            }
            bfrag[kc][g] = v;
        }
    }
    const float* bb = l2w ? b2 : b1;
    const float4 bias4 = make_float4(bb[j], bb[128 + j], bb[256 + j], bb[384 + j]);

    // per-thread base into the fragment-layout W (shorts)
    const int KC = l2w ? 4 : 2;
    const short8* wtb = (const short8*)(wsf + (l2w ? 32768 : 0)
                                            + (size_t)(j * 4 + quad) * KC * 32);

    const float* xb    = x + (size_t)b * SEQT * FEAT;
    float*       out_b = out + (size_t)b * SEQT * HID;

    if (!l2w && tid < 256) {   // prologue: stage x chunk 0 (padded LDS)
        float4 v = ((const float4*)xb)[tid];
        *(float4*)&xs[(tid >> 4) * XSP + ((tid & 15) << 2)] = v;
    }
    if (tid < HID) hA1[0][tid] = 0;                 // h(-1) = 0
    else if (tid < 2 * HID) hA2[0][tid - HID] = 0;
    float cst = 0.0f;                                // cell state (dup x4 quads)
    floatx4 zero4 = {0.f, 0.f, 0.f, 0.f};
    __syncthreads();

    short (*hAp)[HID] = l2w ? hA2 : hA1;
    float* myxz       = l2w ? xz2 : xz1;

    // 129 chunk-iterations: l1 active for c<128, l2 active for c>=1 (chunk c-1)
    for (int c = 0; c <= NCHUNK; ++c) {
        const bool act = l2w ? (c >= 1) : (c < NCHUNK);
        float4 pf;
        // issue next-x prefetch early (stays in flight across the whole chunk;
        // step barriers are lgkm-only so it is never force-drained)
        if (!l2w && c + 1 < NCHUNK && tid < 256)
            pf = ((const float4*)(xb + (size_t)(c + 1) * CHUNK * FEAT))[tid];

        // ---- phase A: build xz chunk = A @ Wfrag + bias (M=16 timesteps) ----
        if (act) {
            floatx4 accp[4] = {zero4, zero4, zero4, zero4};
            for (int kc = 0; kc < KC; ++kc) {
                short8 aop;
                if (!l2w) {              // A = x chunk (fp32 -> bf16)
                    const float* p = &xs[c16 * XSP + kc * 32 + quad * 8];
                    float4 f0 = *(const float4*)p;
                    float4 f1 = *(const float4*)(p + 4);
                    aop[0] = (short)f2bf_(f0.x); aop[1] = (short)f2bf_(f0.y);
                    aop[2] = (short)f2bf_(f0.z); aop[3] = (short)f2bf_(f0.w);
                    aop[4] = (short)f2bf_(f1.x); aop[5] = (short)f2bf_(f1.y);
                    aop[6] = (short)f2bf_(f1.z); aop[7] = (short)f2bf_(f1.w);
                } else {                 // A = h1 chunk c-1 from LDS pipe
                    aop = *(const short8*)&h1x[(c + 1) & 1][c16 * H1P + kc * 32 + quad * 8];
                }
                short8 w0 = wtb[kc * 4 + 0], w1 = wtb[kc * 4 + 1];
                short8 w2 = wtb[kc * 4 + 2], w3 = wtb[kc * 4 + 3];
                accp[0] = __builtin_amdgcn_mfma_f32_16x16x32_bf16(aop, w0, accp[0], 0, 0, 0);
                accp[1] = __builtin_amdgcn_mfma_f32_16x16x32_bf16(aop, w1, accp[1], 0, 0, 0);
                accp[2] = __builtin_amdgcn_mfma_f32_16x16x32_bf16(aop, w2, accp[2], 0, 0, 0);
                accp[3] = __builtin_amdgcn_mfma_f32_16x16x32_bf16(aop, w3, accp[3], 0, 0, 0);
            }
            // D mapping: col=lane&15 (j), row=quad*4+reg (timestep)
#pragma unroll
            for (int r = 0; r < 4; ++r) {
                int srow = quad * 4 + r;
                *(float4*)&myxz[srow * XZP + j * 4] =
                    make_float4(accp[0][r] + bias4.x, accp[1][r] + bias4.y,
                                accp[2][r] + bias4.z, accp[3][r] + bias4.w);
            }
        }
        BAR_LGKM();

        // ---- phase B: 16 recurrent steps, shared barrier (1-chunk skew) ----
        for (int s = 0; s < CHUNK; ++s) {
            if (act) {
                const short* hb = &hAp[s & 1][0];
                short8 af[4];
#pragma unroll
                for (int kc = 0; kc < 4; ++kc)
                    af[kc] = *(const short8*)&hb[kc * 32 + quad * 8];
                float4 xq = *(const float4*)&myxz[s * XZP + j * 4];

                floatx4 acc[4];
#pragma unroll
                for (int g = 0; g < 4; ++g)
                    acc[g] = __builtin_amdgcn_mfma_f32_16x16x32_bf16(af[0], bfrag[0][g], zero4, 0, 0, 0);
#pragma unroll
                for (int kc = 1; kc < 4; ++kc)
#pragma unroll
                    for (int g = 0; g < 4; ++g)
                        acc[g] = __builtin_amdgcn_mfma_f32_16x16x32_bf16(af[kc], bfrag[kc][g], acc[g], 0, 0, 0);

                float zi = acc[0][0] + xq.x;
                float zf = acc[1][0] + xq.y;
                float zg = acc[2][0] + xq.z;
                float zo = acc[3][0] + xq.w;
                float ig = sigmoidf_(zi), fg = sigmoidf_(zf);
                float gg = seluf_(zg),   og = sigmoidf_(zo);
                cst = fg * cst + ig * gg;
                float h = og * seluf_(cst);

                if (lane < 16) {         // quad 0 publishes (all quads identical)
                    unsigned short h16 = f2bf_(h);
                    if (!l2w) {
                        hA1[(s + 1) & 1][j] = (short)h16;
                        h1x[c & 1][s * H1P + j] = (short)h16;   // feed l2 next chunk
                    } else {
                        hA2[(s + 1) & 1][j] = (short)h16;
                        // fire-and-forget fp32 store (never drained by barriers)
                        out_b[(size_t)((c - 1) * CHUNK + s) * HID + j] = h;
                    }
                }
            }
            BAR_LGKM();
        }

        // ---- chunk end: install prefetched x chunk ----
        if (!l2w && c + 1 < NCHUNK && tid < 256)
            *(float4*)&xs[(tid >> 4) * XSP + ((tid & 15) << 2)] = pf;
        BAR_LGKM();
    }
}

// ---------- host launch ----------
// ws layout: [0, 192 KB) fragment-layout bf16 W1|W2 (written by prep_weights
// each call; everything else flows through LDS -- no flags, no h1 pipe).
extern "C" void kernel_launch(void* const* d_in, const int* in_sizes, int n_in,
                              void* d_out, int out_size, void* d_ws, size_t ws_size,
                              hipStream_t stream) {
    const float* x  = (const float*)d_in[0];
    const float* W1 = (const float*)d_in[1];
    const float* U1 = (const float*)d_in[2];
    const float* b1 = (const float*)d_in[3];
    const float* W2 = (const float*)d_in[4];
    const float* U2 = (const float*)d_in[5];
    const float* b2 = (const float*)d_in[6];
    float* out = (float*)d_out;

    unsigned short* wsf = (unsigned short*)d_ws;

    prep_weights<<<dim3(48), dim3(256), 0, stream>>>(W1, W2, wsf);

    fused_lstm<<<dim3(BATCH), dim3(1024), 0, stream>>>(
        x, U1, b1, U2, b2, wsf, out);
}